// Round 6
// baseline (558.304 us; speedup 1.0000x reference)
//
#include <hip/hip_runtime.h>
#include <math.h>

// Problem constants (B, L, D, DH from the reference)
#define WS_B  4
#define WS_L  2048
#define WS_D  1024
#define WS_DH 2048
#define WS_M  (WS_B * WS_L)        // 8192 rows (B*L)
#define NCH   32                    // scan chunks per sequence
#define CHUNK (WS_L / NCH)          // 64 timesteps per chunk

typedef __attribute__((ext_vector_type(4))) float     f32x4;
typedef _Float16 f16x8 __attribute__((ext_vector_type(8)));   // MFMA A/B frag (4 VGPRs)
typedef _Float16 f16x4 __attribute__((ext_vector_type(4)));

// s_waitcnt imm encodings (gfx9/CDNA): vm[3:0]=b3:0, vm[5:4]=b15:14, exp=b6:4, lgkm=b11:8
#define WAITCNT_VM48 0xCF70   // vmcnt<=48, ignore exp/lgkm
#define WAITCNT_VM0  0x0F70   // vmcnt==0, ignore exp/lgkm

#define GLDS(gptr, lptr) \
    __builtin_amdgcn_global_load_lds( \
        (const __attribute__((address_space(1))) unsigned int*)(gptr), \
        (__attribute__((address_space(3))) unsigned int*)(lptr), 16, 0, 0)

// ---- round fp32 -> fp16 (single rounding, ~2^-12 rel) ----
__global__ void round_f16(const float* __restrict__ src, _Float16* __restrict__ dst, int n) {
    int i = (blockIdx.x * blockDim.x + threadIdx.x) * 4;
    if (i >= n) return;
    f32x4 v = *(const f32x4*)(src + i);
    f16x4 h4;
#pragma unroll
    for (int k = 0; k < 4; ++k) h4[k] = (_Float16)v[k];
    *(f16x4*)(dst + i) = h4;
}

// =================== producer-consumer GEMM1 ===================
// h = x @ W_in^T + b_in.  K=1024, nk=32, ring D=4 slots x (8KB A + 8KB B) = 64 KB.
// 5 waves: 0-3 consumers (64x64 tiles), 4 producer. No __syncthreads in k-loop:
// producer paces with s_waitcnt vmcnt(48) (= 3 slabs of 16 wave-loads in flight),
// signals via monotone LDS counters. This removes the vmcnt(0) barrier-drain convoy
// that capped rounds 2-5 at ~4000-4800 cyc per block-kstep.
#define G1_NK 32
#define G1_D  4
__global__ __launch_bounds__(320, 2)
void gemm1_pc(const _Float16* __restrict__ A, const _Float16* __restrict__ B,
              const float* __restrict__ bias, float* __restrict__ C)
{
    const int K = WS_D, ldc = WS_DH;
    __shared__ alignas(16) _Float16 sA[G1_D][4][128][8];
    __shared__ alignas(16) _Float16 sB[G1_D][4][128][8];
    __shared__ int fready, fdone;

    const int tid  = threadIdx.x;
    const int lane = tid & 63;
    const int wv   = tid >> 6;
    if (tid == 0) { fready = 0; fdone = 0; }
    __syncthreads();

    const int bm = blockIdx.x, bn = blockIdx.y;
    const size_t a_base = (size_t)bm * 128 * K;
    const size_t b_base = (size_t)bn * 128 * K;

    if (wv == 4) {
        // ---- producer ----
        auto issue = [&](int k, int slot) {
            int k0 = k * 32;
#pragma unroll
            for (int j = 0; j < 8; ++j) {
                int c   = j * 64 + lane;
                int row = c & 127;
                int kq  = c >> 7;           // uniform within instruction
                GLDS(A + a_base + (size_t)row * K + k0 + kq * 8, &sA[slot][kq][row][0]);
                GLDS(B + b_base + (size_t)row * K + k0 + kq * 8, &sB[slot][kq][row][0]);
            }
        };
#pragma unroll
        for (int k = 0; k < G1_D; ++k) issue(k, k);
        int slot = 0;
        for (int k = 0; k < G1_NK; ++k) {
            if (k <= G1_NK - G1_D) __builtin_amdgcn_s_waitcnt(WAITCNT_VM48);  // slab k landed
            else                   __builtin_amdgcn_s_waitcnt(WAITCNT_VM0);
            if (lane == 0)
                __hip_atomic_store(&fready, k + 1, __ATOMIC_RELEASE, __HIP_MEMORY_SCOPE_WORKGROUP);
            if (k < G1_NK - G1_D) {
                // refill slot with slab k+D once all 4 consumers finished slab k
                while (__hip_atomic_load(&fdone, __ATOMIC_ACQUIRE, __HIP_MEMORY_SCOPE_WORKGROUP)
                       < 4 * (k + 1)) {}
                issue(k + G1_D, slot);
            }
            if (++slot == G1_D) slot = 0;
        }
    } else {
        // ---- consumer ----
        const int wm  = (wv >> 1) * 64;
        const int wn  = (wv & 1) * 64;
        const int m15 = lane & 15;
        const int q   = lane >> 4;
        f32x4 acc[4][4] = {};
        int slot = 0;
        for (int k = 0; k < G1_NK; ++k) {
            while (__hip_atomic_load(&fready, __ATOMIC_ACQUIRE, __HIP_MEMORY_SCOPE_WORKGROUP)
                   < k + 1) {}
            f16x8 af[4], bf[4];
#pragma unroll
            for (int i = 0; i < 4; ++i) {
                af[i] = *(const f16x8*)&sA[slot][q][wm + i * 16 + m15][0];
                bf[i] = *(const f16x8*)&sB[slot][q][wn + i * 16 + m15][0];
            }
#pragma unroll
            for (int i = 0; i < 4; ++i)
#pragma unroll
                for (int j = 0; j < 4; ++j)
                    acc[i][j] = __builtin_amdgcn_mfma_f32_16x16x32_f16(af[i], bf[j], acc[i][j], 0, 0, 0);
            // signal after MFMAs consumed the frags (safe ordering vs slot reuse)
            if (lane == 0)
                __hip_atomic_fetch_add(&fdone, 1, __ATOMIC_RELEASE, __HIP_MEMORY_SCOPE_WORKGROUP);
            if (++slot == G1_D) slot = 0;
        }
        const int r4 = (lane >> 4) * 4;   // C/D: col=lane&15, row=(lane>>4)*4+reg (m89)
#pragma unroll
        for (int j = 0; j < 4; ++j) {
            int col = bn * 128 + wn + j * 16 + m15;
            float bv = bias[col];
#pragma unroll
            for (int i = 0; i < 4; ++i) {
                int row0 = bm * 128 + wm + i * 16 + r4;
#pragma unroll
                for (int r = 0; r < 4; ++r)
                    C[(size_t)(row0 + r) * ldc + col] = acc[i][j][r] + bv;
            }
        }
    }
}

// =================== producer-consumer GEMM2 ===================
// out = (yh + yl) @ W^T + bias.  K=2048, nk=64, ring D=3 slots x 24 KB = 72 KB.
// Producer streams 3 arrays (24 wave-loads/slab); vmcnt(48) = 2 slabs in flight.
#define G2_NK 64
#define G2_D  3
__global__ __launch_bounds__(320, 2)
void gemm2_pc(const _Float16* __restrict__ Ah, const _Float16* __restrict__ Al,
              const _Float16* __restrict__ B,
              const float* __restrict__ bias, float* __restrict__ C)
{
    const int K = WS_DH, ldc = WS_D;
    __shared__ alignas(16) _Float16 sAh[G2_D][4][128][8];
    __shared__ alignas(16) _Float16 sAl[G2_D][4][128][8];
    __shared__ alignas(16) _Float16 sB [G2_D][4][128][8];
    __shared__ int fready, fdone;

    const int tid  = threadIdx.x;
    const int lane = tid & 63;
    const int wv   = tid >> 6;
    if (tid == 0) { fready = 0; fdone = 0; }
    __syncthreads();

    const int bm = blockIdx.x, bn = blockIdx.y;
    const size_t a_base = (size_t)bm * 128 * K;
    const size_t b_base = (size_t)bn * 128 * K;

    if (wv == 4) {
        auto issue = [&](int k, int slot) {
            int k0 = k * 32;
#pragma unroll
            for (int j = 0; j < 8; ++j) {
                int c   = j * 64 + lane;
                int row = c & 127;
                int kq  = c >> 7;
                size_t ga = a_base + (size_t)row * K + k0 + kq * 8;
                GLDS(Ah + ga, &sAh[slot][kq][row][0]);
                GLDS(Al + ga, &sAl[slot][kq][row][0]);
                GLDS(B + b_base + (size_t)row * K + k0 + kq * 8, &sB[slot][kq][row][0]);
            }
        };
#pragma unroll
        for (int k = 0; k < G2_D; ++k) issue(k, k);
        int slot = 0;
        for (int k = 0; k < G2_NK; ++k) {
            if (k <= G2_NK - G2_D) __builtin_amdgcn_s_waitcnt(WAITCNT_VM48);  // (D-1)*24=48
            else                   __builtin_amdgcn_s_waitcnt(WAITCNT_VM0);
            if (lane == 0)
                __hip_atomic_store(&fready, k + 1, __ATOMIC_RELEASE, __HIP_MEMORY_SCOPE_WORKGROUP);
            if (k < G2_NK - G2_D) {
                while (__hip_atomic_load(&fdone, __ATOMIC_ACQUIRE, __HIP_MEMORY_SCOPE_WORKGROUP)
                       < 4 * (k + 1)) {}
                issue(k + G2_D, slot);
            }
            if (++slot == G2_D) slot = 0;
        }
    } else {
        const int wm  = (wv >> 1) * 64;
        const int wn  = (wv & 1) * 64;
        const int m15 = lane & 15;
        const int q   = lane >> 4;
        f32x4 acc[4][4] = {};
        int slot = 0;
        for (int k = 0; k < G2_NK; ++k) {
            while (__hip_atomic_load(&fready, __ATOMIC_ACQUIRE, __HIP_MEMORY_SCOPE_WORKGROUP)
                   < k + 1) {}
            f16x8 afh[4], afl[4], bf[4];
#pragma unroll
            for (int i = 0; i < 4; ++i) {
                afh[i] = *(const f16x8*)&sAh[slot][q][wm + i * 16 + m15][0];
                afl[i] = *(const f16x8*)&sAl[slot][q][wm + i * 16 + m15][0];
                bf[i]  = *(const f16x8*)&sB [slot][q][wn + i * 16 + m15][0];
            }
#pragma unroll
            for (int i = 0; i < 4; ++i)
#pragma unroll
                for (int j = 0; j < 4; ++j) {
                    acc[i][j] = __builtin_amdgcn_mfma_f32_16x16x32_f16(afh[i], bf[j], acc[i][j], 0, 0, 0);
                    acc[i][j] = __builtin_amdgcn_mfma_f32_16x16x32_f16(afl[i], bf[j], acc[i][j], 0, 0, 0);
                }
            if (lane == 0)
                __hip_atomic_fetch_add(&fdone, 1, __ATOMIC_RELEASE, __HIP_MEMORY_SCOPE_WORKGROUP);
            if (++slot == G2_D) slot = 0;
        }
        const int r4 = (lane >> 4) * 4;
#pragma unroll
        for (int j = 0; j < 4; ++j) {
            int col = bn * 128 + wn + j * 16 + m15;
            float bv = bias[col];
#pragma unroll
            for (int i = 0; i < 4; ++i) {
                int row0 = bm * 128 + wm + i * 16 + r4;
#pragma unroll
                for (int r = 0; r < 4; ++r)
                    C[(size_t)(row0 + r) * ldc + col] = acc[i][j][r] + bv;
            }
        }
    }
}

// ---- scan: U[t] = p*U[t-1] + p0*h[t], U[-1]=last;  z[t]=Re(U[t]); y=silu(z) ----
__device__ inline void compute_p(const float* __restrict__ phazor, int c, float& pre, float& pim) {
    float zr = phazor[2 * c], zi = phazor[2 * c + 1];
    float pa = sqrtf(zr * zr + zi * zi);
    float sc = expf(-pa) / pa;       // unit phase * exp(-|p|) magnitude
    pre = zr * sc;
    pim = zi * sc;
}

// phase 1: per-chunk local scan (init 0), write chunk-end state
__global__ void scan_local(const float* __restrict__ h, const float* __restrict__ phazor,
                           const float* __restrict__ phazor_init, float* __restrict__ Uend) {
    int idx = blockIdx.x * blockDim.x + threadIdx.x;      // [0, B*NCH*DH)
    if (idx >= WS_B * NCH * WS_DH) return;
    int c  = idx & (WS_DH - 1);
    int bj = idx >> 11;
    int j  = bj & (NCH - 1);
    int b  = bj >> 5;
    float pre, pim;
    compute_p(phazor, c, pre, pim);
    float p0r = phazor_init[2 * c], p0i = phazor_init[2 * c + 1];
    const float* hp = h + ((size_t)(b * WS_L + j * CHUNK)) * WS_DH + c;
    float ur = 0.f, ui = 0.f;
    for (int t = 0; t < CHUNK; t += 8) {
        float hv[8];
#pragma unroll
        for (int u = 0; u < 8; ++u) hv[u] = hp[(size_t)(t + u) * WS_DH];
#pragma unroll
        for (int u = 0; u < 8; ++u) {
            float nr = fmaf(pre, ur, fmaf(-pim, ui, p0r * hv[u]));
            float ni = fmaf(pre, ui, fmaf( pim, ur, p0i * hv[u]));
            ur = nr; ui = ni;
        }
    }
    Uend[2 * idx] = ur;
    Uend[2 * idx + 1] = ui;
}

// phase 2: serial combine over chunks; carry[j] = full state entering chunk j
__global__ void scan_carry(const float* __restrict__ Uend, float* __restrict__ carry,
                           const float* __restrict__ phazor,
                           const float* __restrict__ last_re, const float* __restrict__ last_im) {
    int idx = blockIdx.x * blockDim.x + threadIdx.x;      // [0, B*DH)
    if (idx >= WS_B * WS_DH) return;
    int c = idx & (WS_DH - 1);
    int b = idx >> 11;
    float pre, pim;
    compute_p(phazor, c, pre, pim);
    float qr = pre, qi = pim;                              // p^CHUNK via 6 squarings (CHUNK=64)
#pragma unroll
    for (int s = 0; s < 6; ++s) {
        float nr = qr * qr - qi * qi;
        qi = 2.f * qr * qi;
        qr = nr;
    }
    float ur = last_re[idx], ui = last_im[idx];            // U[-1] = last
    for (int j = 0; j < NCH; ++j) {
        int o = (b * NCH + j) * WS_DH + c;
        carry[2 * o] = ur;
        carry[2 * o + 1] = ui;
        float Lr = Uend[2 * o], Li = Uend[2 * o + 1];
        float nr = fmaf(qr, ur, fmaf(-qi, ui, Lr));
        float ni = fmaf(qr, ui, fmaf( qi, ur, Li));
        ur = nr; ui = ni;
    }
}

// phase 3: re-scan each chunk from its carry, apply silu, write y as fp16 hi/lo
__global__ void scan_apply(const float* __restrict__ h, const float* __restrict__ phazor,
                           const float* __restrict__ phazor_init, const float* __restrict__ carry,
                           _Float16* __restrict__ yh, _Float16* __restrict__ yl) {
    int idx = blockIdx.x * blockDim.x + threadIdx.x;
    if (idx >= WS_B * NCH * WS_DH) return;
    int c  = idx & (WS_DH - 1);
    int bj = idx >> 11;
    int j  = bj & (NCH - 1);
    int b  = bj >> 5;
    float pre, pim;
    compute_p(phazor, c, pre, pim);
    float p0r = phazor_init[2 * c], p0i = phazor_init[2 * c + 1];
    float ur = carry[2 * idx], ui = carry[2 * idx + 1];
    const size_t base = ((size_t)(b * WS_L + j * CHUNK)) * WS_DH + c;
    const float* hp = h + base;
    for (int t = 0; t < CHUNK; t += 8) {
        float hv[8];
#pragma unroll
        for (int u = 0; u < 8; ++u) hv[u] = hp[(size_t)(t + u) * WS_DH];
#pragma unroll
        for (int u = 0; u < 8; ++u) {
            float nr = fmaf(pre, ur, fmaf(-pim, ui, p0r * hv[u]));
            float ni = fmaf(pre, ui, fmaf( pim, ur, p0i * hv[u]));
            ur = nr; ui = ni;
            float z  = ur;                                  // Re(U[t])
            float yv = z / (1.f + expf(-z));                // silu
            _Float16 hh = (_Float16)yv;
            size_t o = base + (size_t)(t + u) * WS_DH;
            yh[o] = hh;
            yl[o] = (_Float16)(yv - (float)hh);
        }
    }
}

extern "C" void kernel_launch(void* const* d_in, const int* in_sizes, int n_in,
                              void* d_out, int out_size, void* d_ws, size_t ws_size,
                              hipStream_t stream)
{
    const float* x       = (const float*)d_in[0];
    const float* W_in    = (const float*)d_in[1];
    const float* b_in    = (const float*)d_in[2];
    const float* W_out   = (const float*)d_in[3];
    const float* b_out   = (const float*)d_in[4];
    const float* phazor  = (const float*)d_in[5];
    const float* ph_init = (const float*)d_in[6];
    const float* last_re = (const float*)d_in[7];
    const float* last_im = (const float*)d_in[8];
    float* out = (float*)d_out;

    // workspace carve-up (~156 MB)
    char* ws = (char*)d_ws;
    size_t off = 0;
    auto alloc = [&](size_t bytes) {
        char* p = ws + off;
        off += (bytes + 255) & ~(size_t)255;
        return p;
    };
    _Float16* xh    = (_Float16*)alloc((size_t)WS_M * WS_D * 2);     // 16 MB
    _Float16* w1    = (_Float16*)alloc((size_t)WS_DH * WS_D * 2);    //  4 MB
    _Float16* w2    = (_Float16*)alloc((size_t)WS_D * WS_DH * 2);    //  4 MB
    float*    h     = (float*)alloc((size_t)WS_M * WS_DH * 4);       // 64 MB
    _Float16* yh    = (_Float16*)alloc((size_t)WS_M * WS_DH * 2);    // 32 MB
    _Float16* yl    = (_Float16*)alloc((size_t)WS_M * WS_DH * 2);    // 32 MB
    float*    Uend  = (float*)alloc((size_t)WS_B * NCH * WS_DH * 2 * 4);
    float*    carry = (float*)alloc((size_t)WS_B * NCH * WS_DH * 2 * 4);

    // 1) round inputs to fp16
    {
        int n = WS_M * WS_D;
        round_f16<<<dim3(n / 4 / 256), dim3(256), 0, stream>>>(x, xh, n);
        n = WS_DH * WS_D;
        round_f16<<<dim3(n / 4 / 256), dim3(256), 0, stream>>>(W_in, w1, n);
        n = WS_D * WS_DH;
        round_f16<<<dim3(n / 4 / 256), dim3(256), 0, stream>>>(W_out, w2, n);
    }

    // 2) h = x @ W_in^T + b_in   [8192, 2048], grid 64x16, 320 threads (4 consumer + 1 producer)
    {
        dim3 g(WS_M / 128, WS_DH / 128);
        gemm1_pc<<<g, dim3(320), 0, stream>>>(xh, w1, b_in, h);
    }

    // 3) chunked complex scan + silu -> yh/yl (fp16)
    {
        int total = WS_B * NCH * WS_DH;
        scan_local<<<dim3(total / 256), dim3(256), 0, stream>>>(h, phazor, ph_init, Uend);
        scan_carry<<<dim3(WS_B * WS_DH / 256), dim3(256), 0, stream>>>(Uend, carry, phazor,
                                                                       last_re, last_im);
        scan_apply<<<dim3(total / 256), dim3(256), 0, stream>>>(h, phazor, ph_init, carry, yh, yl);
    }

    // 4) out = (yh + yl) @ W_out^T + b_out, K=2048, grid 64x8, 320 threads
    {
        dim3 g(WS_M / 128, WS_D / 128);
        gemm2_pc<<<g, dim3(320), 0, stream>>>(yh, yl, w2, b_out, out);
    }
}

// Round 7
// 375.552 us; speedup vs baseline: 1.4866x; 1.4866x over previous
//
#include <hip/hip_runtime.h>
#include <math.h>

// Problem constants (B, L, D, DH from the reference)
#define WS_B  4
#define WS_L  2048
#define WS_D  1024
#define WS_DH 2048
#define WS_M  (WS_B * WS_L)        // 8192 rows (B*L)
#define NCH   32                    // scan chunks per sequence
#define CHUNK (WS_L / NCH)          // 64 timesteps per chunk

typedef __attribute__((ext_vector_type(4))) float     f32x4;
typedef _Float16 f16x8 __attribute__((ext_vector_type(8)));   // MFMA A/B frag (4 VGPRs)
typedef _Float16 f16x4 __attribute__((ext_vector_type(4)));

#define GLDS(gptr, lptr) \
    __builtin_amdgcn_global_load_lds( \
        (const __attribute__((address_space(1))) unsigned int*)(gptr), \
        (__attribute__((address_space(3))) unsigned int*)(lptr), 16, 0, 0)

// ---- round fp32 -> fp16 (single rounding, ~2^-12 rel) ----
__global__ void round_f16(const float* __restrict__ src, _Float16* __restrict__ dst, int n) {
    int i = (blockIdx.x * blockDim.x + threadIdx.x) * 4;
    if (i >= n) return;
    f32x4 v = *(const f32x4*)(src + i);
    f16x4 h4;
#pragma unroll
    for (int k = 0; k < 4; ++k) h4[k] = (_Float16)v[k];
    *(f16x4*)(dst + i) = h4;
}

// GEMM1: h = x @ W_in^T + b_in.  128x128 tile, BK=64, single-buffer 2-barrier.
// Cross-round fit: per-kstep period is ~constant (~2.5-4.8k cyc) regardless of staged
// bytes (R1 32KB/3470, R3 16KB/2777, R5 24KB/2437) -> amortize the fixed sync cost
// over 2x MFMA by doubling the K-slab. 16 ksteps instead of 32.
__global__ __launch_bounds__(256, 4)
void gemm1_f16(const _Float16* __restrict__ A, const _Float16* __restrict__ B,
               const float* __restrict__ bias, float* __restrict__ C)
{
    const int K = WS_D, ldc = WS_DH;
    __shared__ alignas(16) _Float16 sA[8][128][8];   // 16 KB (128 rows x 64 k)
    __shared__ alignas(16) _Float16 sB[8][128][8];   // 16 KB

    const int tid  = threadIdx.x;
    const int lane = tid & 63;
    const int wave = tid >> 6;
    const int wm   = (wave >> 1) * 64;
    const int wn   = (wave & 1) * 64;
    const int m15  = lane & 15;
    const int q    = lane >> 4;

    const int bm = blockIdx.x;
    const int bn = blockIdx.y;
    const size_t a_base = (size_t)bm * 128 * K;
    const size_t b_base = (size_t)bn * 128 * K;

    f32x4 acc[4][4] = {};

    for (int k0 = 0; k0 < K; k0 += 64) {
        __syncthreads();                 // prev iteration's ds_reads retired
#pragma unroll
        for (int i = 0; i < 4; ++i) {    // 1024 16B chunks per matrix, 4/thread
            int c   = i * 256 + tid;
            int row = c & 127;
            int kq  = c >> 7;            // 0..7, wave-uniform
            size_t ga = a_base + (size_t)row * K + k0 + kq * 8;
            size_t gb = b_base + (size_t)row * K + k0 + kq * 8;
            GLDS(A + ga, &sA[kq][row][0]);
            GLDS(B + gb, &sB[kq][row][0]);
        }
        __syncthreads();                 // drain global_load_lds
#pragma unroll
        for (int kh = 0; kh < 2; ++kh) {
            f16x8 af[4], bf[4];
#pragma unroll
            for (int i = 0; i < 4; ++i) {
                af[i] = *(const f16x8*)&sA[kh * 4 + q][wm + i * 16 + m15][0];
                bf[i] = *(const f16x8*)&sB[kh * 4 + q][wn + i * 16 + m15][0];
            }
#pragma unroll
            for (int i = 0; i < 4; ++i)
#pragma unroll
                for (int j = 0; j < 4; ++j)
                    acc[i][j] = __builtin_amdgcn_mfma_f32_16x16x32_f16(af[i], bf[j], acc[i][j], 0, 0, 0);
        }
    }

    const int r4 = (lane >> 4) * 4;   // C/D: col=lane&15, row=(lane>>4)*4+reg (m89)
#pragma unroll
    for (int j = 0; j < 4; ++j) {
        int col = bn * 128 + wn + j * 16 + m15;
        float bv = bias[col];
#pragma unroll
        for (int i = 0; i < 4; ++i) {
            int row0 = bm * 128 + wm + i * 16 + r4;
#pragma unroll
            for (int r = 0; r < 4; ++r)
                C[(size_t)(row0 + r) * ldc + col] = acc[i][j][r] + bv;
        }
    }
}

// GEMM2 shared-B: out = (yh + yl) @ W^T + bias.  K=2048, BK=64, 48 KB LDS, 32 ksteps.
// 64 MFMA/wave per kstep against the ~fixed per-kstep sync cost.
__global__ __launch_bounds__(256, 3)
void gemm2_f16(const _Float16* __restrict__ Ah, const _Float16* __restrict__ Al,
               const _Float16* __restrict__ B,
               const float* __restrict__ bias, float* __restrict__ C)
{
    const int K = WS_DH, ldc = WS_D;
    __shared__ alignas(16) _Float16 sAh[8][128][8];
    __shared__ alignas(16) _Float16 sAl[8][128][8];
    __shared__ alignas(16) _Float16 sB [8][128][8];

    const int tid  = threadIdx.x;
    const int lane = tid & 63;
    const int wave = tid >> 6;
    const int wm   = (wave >> 1) * 64;
    const int wn   = (wave & 1) * 64;
    const int m15  = lane & 15;
    const int q    = lane >> 4;

    const int bm = blockIdx.x;
    const int bn = blockIdx.y;
    const size_t a_base = (size_t)bm * 128 * K;
    const size_t b_base = (size_t)bn * 128 * K;

    f32x4 acc[4][4] = {};

    for (int k0 = 0; k0 < K; k0 += 64) {
        __syncthreads();
#pragma unroll
        for (int i = 0; i < 4; ++i) {
            int c   = i * 256 + tid;
            int row = c & 127;
            int kq  = c >> 7;
            size_t ga = a_base + (size_t)row * K + k0 + kq * 8;
            size_t gb = b_base + (size_t)row * K + k0 + kq * 8;
            GLDS(Ah + ga, &sAh[kq][row][0]);
            GLDS(Al + ga, &sAl[kq][row][0]);
            GLDS(B + gb, &sB[kq][row][0]);
        }
        __syncthreads();
#pragma unroll
        for (int kh = 0; kh < 2; ++kh) {
            f16x8 afh[4], afl[4], bf[4];
#pragma unroll
            for (int i = 0; i < 4; ++i) {
                afh[i] = *(const f16x8*)&sAh[kh * 4 + q][wm + i * 16 + m15][0];
                afl[i] = *(const f16x8*)&sAl[kh * 4 + q][wm + i * 16 + m15][0];
                bf[i]  = *(const f16x8*)&sB [kh * 4 + q][wn + i * 16 + m15][0];
            }
#pragma unroll
            for (int i = 0; i < 4; ++i)
#pragma unroll
                for (int j = 0; j < 4; ++j) {
                    acc[i][j] = __builtin_amdgcn_mfma_f32_16x16x32_f16(afh[i], bf[j], acc[i][j], 0, 0, 0);
                    acc[i][j] = __builtin_amdgcn_mfma_f32_16x16x32_f16(afl[i], bf[j], acc[i][j], 0, 0, 0);
                }
        }
    }

    const int r4 = (lane >> 4) * 4;
#pragma unroll
    for (int j = 0; j < 4; ++j) {
        int col = bn * 128 + wn + j * 16 + m15;
        float bv = bias[col];
#pragma unroll
        for (int i = 0; i < 4; ++i) {
            int row0 = bm * 128 + wm + i * 16 + r4;
#pragma unroll
            for (int r = 0; r < 4; ++r)
                C[(size_t)(row0 + r) * ldc + col] = acc[i][j][r] + bv;
        }
    }
}

// ---- scan: U[t] = p*U[t-1] + p0*h[t], U[-1]=last;  z[t]=Re(U[t]); y=silu(z) ----
__device__ inline void compute_p(const float* __restrict__ phazor, int c, float& pre, float& pim) {
    float zr = phazor[2 * c], zi = phazor[2 * c + 1];
    float pa = sqrtf(zr * zr + zi * zi);
    float sc = expf(-pa) / pa;       // unit phase * exp(-|p|) magnitude
    pre = zr * sc;
    pim = zi * sc;
}

// phase 1: per-chunk local scan (init 0), write chunk-end state
__global__ void scan_local(const float* __restrict__ h, const float* __restrict__ phazor,
                           const float* __restrict__ phazor_init, float* __restrict__ Uend) {
    int idx = blockIdx.x * blockDim.x + threadIdx.x;      // [0, B*NCH*DH)
    if (idx >= WS_B * NCH * WS_DH) return;
    int c  = idx & (WS_DH - 1);
    int bj = idx >> 11;
    int j  = bj & (NCH - 1);
    int b  = bj >> 5;
    float pre, pim;
    compute_p(phazor, c, pre, pim);
    float p0r = phazor_init[2 * c], p0i = phazor_init[2 * c + 1];
    const float* hp = h + ((size_t)(b * WS_L + j * CHUNK)) * WS_DH + c;
    float ur = 0.f, ui = 0.f;
    for (int t = 0; t < CHUNK; t += 8) {
        float hv[8];
#pragma unroll
        for (int u = 0; u < 8; ++u) hv[u] = hp[(size_t)(t + u) * WS_DH];
#pragma unroll
        for (int u = 0; u < 8; ++u) {
            float nr = fmaf(pre, ur, fmaf(-pim, ui, p0r * hv[u]));
            float ni = fmaf(pre, ui, fmaf( pim, ur, p0i * hv[u]));
            ur = nr; ui = ni;
        }
    }
    Uend[2 * idx] = ur;
    Uend[2 * idx + 1] = ui;
}

// phase 2: serial combine over chunks; carry[j] = full state entering chunk j
__global__ void scan_carry(const float* __restrict__ Uend, float* __restrict__ carry,
                           const float* __restrict__ phazor,
                           const float* __restrict__ last_re, const float* __restrict__ last_im) {
    int idx = blockIdx.x * blockDim.x + threadIdx.x;      // [0, B*DH)
    if (idx >= WS_B * WS_DH) return;
    int c = idx & (WS_DH - 1);
    int b = idx >> 11;
    float pre, pim;
    compute_p(phazor, c, pre, pim);
    float qr = pre, qi = pim;                              // p^CHUNK via 6 squarings (CHUNK=64)
#pragma unroll
    for (int s = 0; s < 6; ++s) {
        float nr = qr * qr - qi * qi;
        qi = 2.f * qr * qi;
        qr = nr;
    }
    float ur = last_re[idx], ui = last_im[idx];            // U[-1] = last
    for (int j = 0; j < NCH; ++j) {
        int o = (b * NCH + j) * WS_DH + c;
        carry[2 * o] = ur;
        carry[2 * o + 1] = ui;
        float Lr = Uend[2 * o], Li = Uend[2 * o + 1];
        float nr = fmaf(qr, ur, fmaf(-qi, ui, Lr));
        float ni = fmaf(qr, ui, fmaf( qi, ur, Li));
        ur = nr; ui = ni;
    }
}

// phase 3: re-scan each chunk from its carry, apply silu, write y as fp16 hi/lo
__global__ void scan_apply(const float* __restrict__ h, const float* __restrict__ phazor,
                           const float* __restrict__ phazor_init, const float* __restrict__ carry,
                           _Float16* __restrict__ yh, _Float16* __restrict__ yl) {
    int idx = blockIdx.x * blockDim.x + threadIdx.x;
    if (idx >= WS_B * NCH * WS_DH) return;
    int c  = idx & (WS_DH - 1);
    int bj = idx >> 11;
    int j  = bj & (NCH - 1);
    int b  = bj >> 5;
    float pre, pim;
    compute_p(phazor, c, pre, pim);
    float p0r = phazor_init[2 * c], p0i = phazor_init[2 * c + 1];
    float ur = carry[2 * idx], ui = carry[2 * idx + 1];
    const size_t base = ((size_t)(b * WS_L + j * CHUNK)) * WS_DH + c;
    const float* hp = h + base;
    for (int t = 0; t < CHUNK; t += 8) {
        float hv[8];
#pragma unroll
        for (int u = 0; u < 8; ++u) hv[u] = hp[(size_t)(t + u) * WS_DH];
#pragma unroll
        for (int u = 0; u < 8; ++u) {
            float nr = fmaf(pre, ur, fmaf(-pim, ui, p0r * hv[u]));
            float ni = fmaf(pre, ui, fmaf( pim, ur, p0i * hv[u]));
            ur = nr; ui = ni;
            float z  = ur;                                  // Re(U[t])
            float yv = z / (1.f + expf(-z));                // silu
            _Float16 hh = (_Float16)yv;
            size_t o = base + (size_t)(t + u) * WS_DH;
            yh[o] = hh;
            yl[o] = (_Float16)(yv - (float)hh);
        }
    }
}

extern "C" void kernel_launch(void* const* d_in, const int* in_sizes, int n_in,
                              void* d_out, int out_size, void* d_ws, size_t ws_size,
                              hipStream_t stream)
{
    const float* x       = (const float*)d_in[0];
    const float* W_in    = (const float*)d_in[1];
    const float* b_in    = (const float*)d_in[2];
    const float* W_out   = (const float*)d_in[3];
    const float* b_out   = (const float*)d_in[4];
    const float* phazor  = (const float*)d_in[5];
    const float* ph_init = (const float*)d_in[6];
    const float* last_re = (const float*)d_in[7];
    const float* last_im = (const float*)d_in[8];
    float* out = (float*)d_out;

    // workspace carve-up (~156 MB)
    char* ws = (char*)d_ws;
    size_t off = 0;
    auto alloc = [&](size_t bytes) {
        char* p = ws + off;
        off += (bytes + 255) & ~(size_t)255;
        return p;
    };
    _Float16* xh    = (_Float16*)alloc((size_t)WS_M * WS_D * 2);     // 16 MB
    _Float16* w1    = (_Float16*)alloc((size_t)WS_DH * WS_D * 2);    //  4 MB
    _Float16* w2    = (_Float16*)alloc((size_t)WS_D * WS_DH * 2);    //  4 MB
    float*    h     = (float*)alloc((size_t)WS_M * WS_DH * 4);       // 64 MB
    _Float16* yh    = (_Float16*)alloc((size_t)WS_M * WS_DH * 2);    // 32 MB
    _Float16* yl    = (_Float16*)alloc((size_t)WS_M * WS_DH * 2);    // 32 MB
    float*    Uend  = (float*)alloc((size_t)WS_B * NCH * WS_DH * 2 * 4);
    float*    carry = (float*)alloc((size_t)WS_B * NCH * WS_DH * 2 * 4);

    // 1) round inputs to fp16
    {
        int n = WS_M * WS_D;
        round_f16<<<dim3(n / 4 / 256), dim3(256), 0, stream>>>(x, xh, n);
        n = WS_DH * WS_D;
        round_f16<<<dim3(n / 4 / 256), dim3(256), 0, stream>>>(W_in, w1, n);
        n = WS_D * WS_DH;
        round_f16<<<dim3(n / 4 / 256), dim3(256), 0, stream>>>(W_out, w2, n);
    }

    // 2) h = x @ W_in^T + b_in   [8192, 2048], grid 64x16 = 1024 blocks, 16 ksteps
    {
        dim3 g(WS_M / 128, WS_DH / 128);
        gemm1_f16<<<g, dim3(256), 0, stream>>>(xh, w1, b_in, h);
    }

    // 3) chunked complex scan + silu -> yh/yl (fp16)
    {
        int total = WS_B * NCH * WS_DH;
        scan_local<<<dim3(total / 256), dim3(256), 0, stream>>>(h, phazor, ph_init, Uend);
        scan_carry<<<dim3(WS_B * WS_DH / 256), dim3(256), 0, stream>>>(Uend, carry, phazor,
                                                                       last_re, last_im);
        scan_apply<<<dim3(total / 256), dim3(256), 0, stream>>>(h, phazor, ph_init, carry, yh, yl);
    }

    // 4) out = (yh + yl) @ W_out^T + b_out, K=2048, grid 64x8 = 512 blocks, 32 ksteps
    {
        dim3 g(WS_M / 128, WS_D / 128);
        gemm2_f16<<<g, dim3(256), 0, stream>>>(yh, yl, w2, b_out, out);
    }
}

// Round 8
// 278.620 us; speedup vs baseline: 2.0038x; 1.3479x over previous
//
#include <hip/hip_runtime.h>
#include <math.h>

// Problem constants (B, L, D, DH from the reference)
#define WS_B  4
#define WS_L  2048
#define WS_D  1024
#define WS_DH 2048
#define WS_M  (WS_B * WS_L)        // 8192 rows (B*L)
#define NCH   32                    // scan chunks per sequence
#define CHUNK (WS_L / NCH)          // 64 timesteps per chunk

typedef __attribute__((ext_vector_type(4))) float     f32x4;
typedef _Float16 f16x8 __attribute__((ext_vector_type(8)));   // MFMA A/B frag (4 VGPRs)
typedef _Float16 f16x4 __attribute__((ext_vector_type(4)));

#define GLDS(gptr, lptr) \
    __builtin_amdgcn_global_load_lds( \
        (const __attribute__((address_space(1))) unsigned int*)(gptr), \
        (__attribute__((address_space(3))) unsigned int*)(lptr), 16, 0, 0)

// ---- pack fp32 row-major [R,K] -> fp16 tile-major P[rb][kc][r][8] ----
// Packed layout mirrors the GEMM's LDS destination, so staging wave-instrs read
// 64 lanes x 16B CONTIGUOUS (8 cache lines) instead of 64-line gathers (the
// ~0.6 req/cyc/CU binder identified from rounds 1-7).
__global__ void pack_f16(const float* __restrict__ src, _Float16* __restrict__ dst,
                         int K, int k8log, int nChunks) {
    int chunk = blockIdx.x * 256 + threadIdx.x;
    if (chunk >= nChunks) return;
    int r    = chunk & 127;
    int rest = chunk >> 7;
    int K8m  = (1 << k8log) - 1;
    int kc   = rest & K8m;
    int rb   = rest >> k8log;
    const float* s = src + ((size_t)(rb * 128 + r) * K + kc * 8);
    f32x4 v0 = *(const f32x4*)s;
    f32x4 v1 = *(const f32x4*)(s + 4);
    f16x8 h;
#pragma unroll
    for (int k = 0; k < 4; ++k) { h[k] = (_Float16)v0[k]; h[4 + k] = (_Float16)v1[k]; }
    *(f16x8*)(dst + (size_t)chunk * 8) = h;   // consecutive threads -> consecutive 16B
}

// GEMM1: h = x @ W_in^T + b_in.  Packed operands, 128x128 tile, BK=32, dbuf,
// single barrier per kstep (R5 structure). Staging fully coalesced.
__global__ __launch_bounds__(256, 4)
void gemm1_f16(const _Float16* __restrict__ A, const _Float16* __restrict__ B,
               const float* __restrict__ bias, float* __restrict__ C)
{
    const int K8 = WS_D / 8, ldc = WS_DH;       // K=1024 -> 128 k-chunks
    __shared__ alignas(16) _Float16 sA[2][4][128][8];
    __shared__ alignas(16) _Float16 sB[2][4][128][8];

    const int tid  = threadIdx.x;
    const int lane = tid & 63;
    const int wave = tid >> 6;
    const int wm   = (wave >> 1) * 64;
    const int wn   = (wave & 1) * 64;
    const int m15  = lane & 15;
    const int q    = lane >> 4;

    const int bm = blockIdx.x;
    const int bn = blockIdx.y;

    f32x4 acc[4][4] = {};

    // kc = k-chunk index (8 elems); one kstep covers 4 chunks (BK=32)
    auto stage = [&](int kc0, int buf) {
#pragma unroll
        for (int i = 0; i < 2; ++i) {
            int c   = i * 256 + tid;     // 512 chunks per matrix
            int row = c & 127;
            int kq  = c >> 7;            // wave-uniform
            size_t ac = ((size_t)(bm * K8 + kc0 + kq) * 128 + row) * 8;
            size_t bc = ((size_t)(bn * K8 + kc0 + kq) * 128 + row) * 8;
            GLDS(A + ac, &sA[buf][kq][row][0]);   // 64 lanes x 16B contiguous
            GLDS(B + bc, &sB[buf][kq][row][0]);
        }
    };

    stage(0, 0);
    int buf = 0;
    for (int kc0 = 0; kc0 < K8; kc0 += 4, buf ^= 1) {
        __syncthreads();                  // drains vmcnt: buf ready, buf^1 reads retired
        if (kc0 + 4 < K8) stage(kc0 + 4, buf ^ 1);

        f16x8 af[4], bf[4];
#pragma unroll
        for (int i = 0; i < 4; ++i) {
            af[i] = *(const f16x8*)&sA[buf][q][wm + i * 16 + m15][0];
            bf[i] = *(const f16x8*)&sB[buf][q][wn + i * 16 + m15][0];
        }
#pragma unroll
        for (int i = 0; i < 4; ++i)
#pragma unroll
            for (int j = 0; j < 4; ++j)
                acc[i][j] = __builtin_amdgcn_mfma_f32_16x16x32_f16(af[i], bf[j], acc[i][j], 0, 0, 0);
    }

    const int r4 = (lane >> 4) * 4;   // C/D: col=lane&15, row=(lane>>4)*4+reg (m89)
#pragma unroll
    for (int j = 0; j < 4; ++j) {
        int col = bn * 128 + wn + j * 16 + m15;
        float bv = bias[col];
#pragma unroll
        for (int i = 0; i < 4; ++i) {
            int row0 = bm * 128 + wm + i * 16 + r4;
#pragma unroll
            for (int r = 0; r < 4; ++r)
                C[(size_t)(row0 + r) * ldc + col] = acc[i][j][r] + bv;
        }
    }
}

// GEMM2 shared-B: out = (yh + yl) @ W_out^T + bias.  K=2048, packed operands,
// BK=32, dbuf, single barrier. 24 KB staged/kstep, all coalesced.
__global__ __launch_bounds__(256, 2)
void gemm2_f16(const _Float16* __restrict__ Ah, const _Float16* __restrict__ Al,
               const _Float16* __restrict__ B,
               const float* __restrict__ bias, float* __restrict__ C)
{
    const int K8 = WS_DH / 8, ldc = WS_D;       // K=2048 -> 256 k-chunks
    __shared__ alignas(16) _Float16 sAh[2][4][128][8];
    __shared__ alignas(16) _Float16 sAl[2][4][128][8];
    __shared__ alignas(16) _Float16 sB [2][4][128][8];

    const int tid  = threadIdx.x;
    const int lane = tid & 63;
    const int wave = tid >> 6;
    const int wm   = (wave >> 1) * 64;
    const int wn   = (wave & 1) * 64;
    const int m15  = lane & 15;
    const int q    = lane >> 4;

    const int bm = blockIdx.x;
    const int bn = blockIdx.y;

    f32x4 acc[4][4] = {};

    auto stage = [&](int kc0, int buf) {
#pragma unroll
        for (int i = 0; i < 2; ++i) {
            int c   = i * 256 + tid;
            int row = c & 127;
            int kq  = c >> 7;
            size_t ac = ((size_t)(bm * K8 + kc0 + kq) * 128 + row) * 8;
            size_t bc = ((size_t)(bn * K8 + kc0 + kq) * 128 + row) * 8;
            GLDS(Ah + ac, &sAh[buf][kq][row][0]);
            GLDS(Al + ac, &sAl[buf][kq][row][0]);
            GLDS(B + bc,  &sB[buf][kq][row][0]);
        }
    };

    stage(0, 0);
    int buf = 0;
    for (int kc0 = 0; kc0 < K8; kc0 += 4, buf ^= 1) {
        __syncthreads();
        if (kc0 + 4 < K8) stage(kc0 + 4, buf ^ 1);

        f16x8 afh[4], afl[4], bf[4];
#pragma unroll
        for (int i = 0; i < 4; ++i) {
            afh[i] = *(const f16x8*)&sAh[buf][q][wm + i * 16 + m15][0];
            afl[i] = *(const f16x8*)&sAl[buf][q][wm + i * 16 + m15][0];
            bf[i]  = *(const f16x8*)&sB [buf][q][wn + i * 16 + m15][0];
        }
#pragma unroll
        for (int i = 0; i < 4; ++i)
#pragma unroll
            for (int j = 0; j < 4; ++j) {
                acc[i][j] = __builtin_amdgcn_mfma_f32_16x16x32_f16(afh[i], bf[j], acc[i][j], 0, 0, 0);
                acc[i][j] = __builtin_amdgcn_mfma_f32_16x16x32_f16(afl[i], bf[j], acc[i][j], 0, 0, 0);
            }
    }

    const int r4 = (lane >> 4) * 4;
#pragma unroll
    for (int j = 0; j < 4; ++j) {
        int col = bn * 128 + wn + j * 16 + m15;
        float bv = bias[col];
#pragma unroll
        for (int i = 0; i < 4; ++i) {
            int row0 = bm * 128 + wm + i * 16 + r4;
#pragma unroll
            for (int r = 0; r < 4; ++r)
                C[(size_t)(row0 + r) * ldc + col] = acc[i][j][r] + bv;
        }
    }
}

// ---- scan: U[t] = p*U[t-1] + p0*h[t], U[-1]=last;  z[t]=Re(U[t]); y=silu(z) ----
__device__ inline void compute_p(const float* __restrict__ phazor, int c, float& pre, float& pim) {
    float zr = phazor[2 * c], zi = phazor[2 * c + 1];
    float pa = sqrtf(zr * zr + zi * zi);
    float sc = expf(-pa) / pa;       // unit phase * exp(-|p|) magnitude
    pre = zr * sc;
    pim = zi * sc;
}

// phase 1: per-chunk local scan (init 0), write chunk-end state
__global__ void scan_local(const float* __restrict__ h, const float* __restrict__ phazor,
                           const float* __restrict__ phazor_init, float* __restrict__ Uend) {
    int idx = blockIdx.x * blockDim.x + threadIdx.x;      // [0, B*NCH*DH)
    if (idx >= WS_B * NCH * WS_DH) return;
    int c  = idx & (WS_DH - 1);
    int bj = idx >> 11;
    int j  = bj & (NCH - 1);
    int b  = bj >> 5;
    float pre, pim;
    compute_p(phazor, c, pre, pim);
    float p0r = phazor_init[2 * c], p0i = phazor_init[2 * c + 1];
    const float* hp = h + ((size_t)(b * WS_L + j * CHUNK)) * WS_DH + c;
    float ur = 0.f, ui = 0.f;
    for (int t = 0; t < CHUNK; t += 8) {
        float hv[8];
#pragma unroll
        for (int u = 0; u < 8; ++u) hv[u] = hp[(size_t)(t + u) * WS_DH];
#pragma unroll
        for (int u = 0; u < 8; ++u) {
            float nr = fmaf(pre, ur, fmaf(-pim, ui, p0r * hv[u]));
            float ni = fmaf(pre, ui, fmaf( pim, ur, p0i * hv[u]));
            ur = nr; ui = ni;
        }
    }
    Uend[2 * idx] = ur;
    Uend[2 * idx + 1] = ui;
}

// phase 2: serial combine over chunks; carry[j] = full state entering chunk j
__global__ void scan_carry(const float* __restrict__ Uend, float* __restrict__ carry,
                           const float* __restrict__ phazor,
                           const float* __restrict__ last_re, const float* __restrict__ last_im) {
    int idx = blockIdx.x * blockDim.x + threadIdx.x;      // [0, B*DH)
    if (idx >= WS_B * WS_DH) return;
    int c = idx & (WS_DH - 1);
    int b = idx >> 11;
    float pre, pim;
    compute_p(phazor, c, pre, pim);
    float qr = pre, qi = pim;                              // p^CHUNK via 6 squarings (CHUNK=64)
#pragma unroll
    for (int s = 0; s < 6; ++s) {
        float nr = qr * qr - qi * qi;
        qi = 2.f * qr * qi;
        qr = nr;
    }
    float ur = last_re[idx], ui = last_im[idx];            // U[-1] = last
    for (int j = 0; j < NCH; ++j) {
        int o = (b * NCH + j) * WS_DH + c;
        carry[2 * o] = ur;
        carry[2 * o + 1] = ui;
        float Lr = Uend[2 * o], Li = Uend[2 * o + 1];
        float nr = fmaf(qr, ur, fmaf(-qi, ui, Lr));
        float ni = fmaf(qr, ui, fmaf( qi, ur, Li));
        ur = nr; ui = ni;
    }
}

// phase 3: re-scan from carry, silu, write y hi/lo DIRECTLY in packed tile-major
// layout P[rb][kc][r][8] (K8=256): per wave-store 8 x 16B fragments (vs 64-line
// gathers if GEMM2 had to stage row-major).
__global__ void scan_apply(const float* __restrict__ h, const float* __restrict__ phazor,
                           const float* __restrict__ phazor_init, const float* __restrict__ carry,
                           _Float16* __restrict__ yh, _Float16* __restrict__ yl) {
    int idx = blockIdx.x * blockDim.x + threadIdx.x;
    if (idx >= WS_B * NCH * WS_DH) return;
    int c  = idx & (WS_DH - 1);
    int bj = idx >> 11;
    int j  = bj & (NCH - 1);
    int b  = bj >> 5;
    float pre, pim;
    compute_p(phazor, c, pre, pim);
    float p0r = phazor_init[2 * c], p0i = phazor_init[2 * c + 1];
    float ur = carry[2 * idx], ui = carry[2 * idx + 1];
    const int row0 = b * WS_L + j * CHUNK;
    const float* hp = h + (size_t)row0 * WS_DH + c;
    const int chi = c >> 3, clo = c & 7;                   // packed column split
    for (int t = 0; t < CHUNK; t += 8) {
        float hv[8];
#pragma unroll
        for (int u = 0; u < 8; ++u) hv[u] = hp[(size_t)(t + u) * WS_DH];
#pragma unroll
        for (int u = 0; u < 8; ++u) {
            float nr = fmaf(pre, ur, fmaf(-pim, ui, p0r * hv[u]));
            float ni = fmaf(pre, ui, fmaf( pim, ur, p0i * hv[u]));
            ur = nr; ui = ni;
            float z  = ur;                                  // Re(U[t])
            float yv = z / (1.f + expf(-z));                // silu
            _Float16 hh = (_Float16)yv;
            int row = row0 + t + u;
            size_t o = (((size_t)(row >> 7) * 256 + chi) * 128 + (row & 127)) * 8 + clo;
            yh[o] = hh;
            yl[o] = (_Float16)(yv - (float)hh);
        }
    }
}

extern "C" void kernel_launch(void* const* d_in, const int* in_sizes, int n_in,
                              void* d_out, int out_size, void* d_ws, size_t ws_size,
                              hipStream_t stream)
{
    const float* x       = (const float*)d_in[0];
    const float* W_in    = (const float*)d_in[1];
    const float* b_in    = (const float*)d_in[2];
    const float* W_out   = (const float*)d_in[3];
    const float* b_out   = (const float*)d_in[4];
    const float* phazor  = (const float*)d_in[5];
    const float* ph_init = (const float*)d_in[6];
    const float* last_re = (const float*)d_in[7];
    const float* last_im = (const float*)d_in[8];
    float* out = (float*)d_out;

    // workspace carve-up (~156 MB)
    char* ws = (char*)d_ws;
    size_t off = 0;
    auto alloc = [&](size_t bytes) {
        char* p = ws + off;
        off += (bytes + 255) & ~(size_t)255;
        return p;
    };
    _Float16* xp    = (_Float16*)alloc((size_t)WS_M * WS_D * 2);     // 16 MB packed
    _Float16* w1p   = (_Float16*)alloc((size_t)WS_DH * WS_D * 2);    //  4 MB packed
    _Float16* w2p   = (_Float16*)alloc((size_t)WS_D * WS_DH * 2);    //  4 MB packed
    float*    h     = (float*)alloc((size_t)WS_M * WS_DH * 4);       // 64 MB
    _Float16* yhp   = (_Float16*)alloc((size_t)WS_M * WS_DH * 2);    // 32 MB packed
    _Float16* ylp   = (_Float16*)alloc((size_t)WS_M * WS_DH * 2);    // 32 MB packed
    float*    Uend  = (float*)alloc((size_t)WS_B * NCH * WS_DH * 2 * 4);
    float*    carry = (float*)alloc((size_t)WS_B * NCH * WS_DH * 2 * 4);

    // 1) pack inputs to fp16 tile-major
    {
        int n = WS_M * WS_D / 8;      // x: R=8192, K=1024, K8=128 (log 7)
        pack_f16<<<dim3((n + 255) / 256), dim3(256), 0, stream>>>(x, xp, WS_D, 7, n);
        n = WS_DH * WS_D / 8;         // W_in: R=2048, K=1024
        pack_f16<<<dim3((n + 255) / 256), dim3(256), 0, stream>>>(W_in, w1p, WS_D, 7, n);
        n = WS_D * WS_DH / 8;         // W_out: R=1024, K=2048, K8=256 (log 8)
        pack_f16<<<dim3((n + 255) / 256), dim3(256), 0, stream>>>(W_out, w2p, WS_DH, 8, n);
    }

    // 2) h = x @ W_in^T + b_in   [8192, 2048], grid 64x16 = 1024 blocks
    {
        dim3 g(WS_M / 128, WS_DH / 128);
        gemm1_f16<<<g, dim3(256), 0, stream>>>(xp, w1p, b_in, h);
    }

    // 3) chunked complex scan + silu -> yh/yl (fp16, packed)
    {
        int total = WS_B * NCH * WS_DH;
        scan_local<<<dim3(total / 256), dim3(256), 0, stream>>>(h, phazor, ph_init, Uend);
        scan_carry<<<dim3(WS_B * WS_DH / 256), dim3(256), 0, stream>>>(Uend, carry, phazor,
                                                                       last_re, last_im);
        scan_apply<<<dim3(total / 256), dim3(256), 0, stream>>>(h, phazor, ph_init, carry, yhp, ylp);
    }

    // 4) out = (yh + yl) @ W_out^T + b_out, K=2048, grid 64x8 = 512 blocks
    {
        dim3 g(WS_M / 128, WS_D / 128);
        gemm2_f16<<<g, dim3(256), 0, stream>>>(yhp, ylp, w2p, b_out, out);
    }
}

// Round 9
// 259.316 us; speedup vs baseline: 2.1530x; 1.0744x over previous
//
#include <hip/hip_runtime.h>
#include <math.h>

// Problem constants (B, L, D, DH from the reference)
#define WS_B  4
#define WS_L  2048
#define WS_D  1024
#define WS_DH 2048
#define WS_M  (WS_B * WS_L)        // 8192 rows (B*L)
#define NCH   32                    // scan chunks per sequence
#define CHUNK (WS_L / NCH)          // 64 timesteps per chunk

typedef __attribute__((ext_vector_type(4))) float     f32x4;
typedef _Float16 f16x8 __attribute__((ext_vector_type(8)));   // MFMA A/B frag (4 VGPRs)
typedef _Float16 f16x4 __attribute__((ext_vector_type(4)));

#define GLDS(gptr, lptr) \
    __builtin_amdgcn_global_load_lds( \
        (const __attribute__((address_space(1))) unsigned int*)(gptr), \
        (__attribute__((address_space(3))) unsigned int*)(lptr), 16, 0, 0)

// ---- pack fp32 row-major [R,K] -> fp16 tile-major P[rb][kc][r][8] ----
// Packed layout mirrors the GEMM's LDS destination: staging wave-instrs read
// 64 lanes x 16B CONTIGUOUS (8 cache lines, not 64) — this was the R8 2x win.
__global__ void pack_f16(const float* __restrict__ src, _Float16* __restrict__ dst,
                         int K, int k8log, int nChunks) {
    int chunk = blockIdx.x * 256 + threadIdx.x;
    if (chunk >= nChunks) return;
    int r    = chunk & 127;
    int rest = chunk >> 7;
    int K8m  = (1 << k8log) - 1;
    int kc   = rest & K8m;
    int rb   = rest >> k8log;
    const float* s = src + ((size_t)(rb * 128 + r) * K + kc * 8);
    f32x4 v0 = *(const f32x4*)s;
    f32x4 v1 = *(const f32x4*)(s + 4);
    f16x8 h;
#pragma unroll
    for (int k = 0; k < 4; ++k) { h[k] = (_Float16)v0[k]; h[4 + k] = (_Float16)v1[k]; }
    *(f16x8*)(dst + (size_t)chunk * 8) = h;   // consecutive threads -> consecutive 16B
}

// ---- unified packed fp16 GEMM:  C[m,n] = sum_k A[m,k]*B[n,k] + bias[n] ----
// Operands in tile-major packed layout. 128x128 tile, BK=32, dbuf, single
// barrier per kstep. 16 KB staged / 16 MFMA/wave per kstep, all coalesced.
// R9: GEMM2's yl correction term dropped (absmax floor is the fp32 scan, not
// GEMM rounding: absmax was bit-identical 0.015625 across rounds 1-8 despite
// 3 different precision schemes). Both GEMMs now share this kernel.
template<int K8, int LDC>
__global__ __launch_bounds__(256, 4)
void gemm_f16_packed(const _Float16* __restrict__ A, const _Float16* __restrict__ B,
                     const float* __restrict__ bias, float* __restrict__ C)
{
    __shared__ alignas(16) _Float16 sA[2][4][128][8];
    __shared__ alignas(16) _Float16 sB[2][4][128][8];

    const int tid  = threadIdx.x;
    const int lane = tid & 63;
    const int wave = tid >> 6;
    const int wm   = (wave >> 1) * 64;
    const int wn   = (wave & 1) * 64;
    const int m15  = lane & 15;
    const int q    = lane >> 4;

    const int bm = blockIdx.x;
    const int bn = blockIdx.y;

    f32x4 acc[4][4] = {};

    // kc = k-chunk index (8 elems); one kstep covers 4 chunks (BK=32)
    auto stage = [&](int kc0, int buf) {
#pragma unroll
        for (int i = 0; i < 2; ++i) {
            int c   = i * 256 + tid;     // 512 chunks per matrix
            int row = c & 127;
            int kq  = c >> 7;            // wave-uniform
            size_t ac = ((size_t)(bm * K8 + kc0 + kq) * 128 + row) * 8;
            size_t bc = ((size_t)(bn * K8 + kc0 + kq) * 128 + row) * 8;
            GLDS(A + ac, &sA[buf][kq][row][0]);   // 64 lanes x 16B contiguous
            GLDS(B + bc, &sB[buf][kq][row][0]);
        }
    };

    stage(0, 0);
    int buf = 0;
    for (int kc0 = 0; kc0 < K8; kc0 += 4, buf ^= 1) {
        __syncthreads();                  // drains vmcnt: buf ready, buf^1 reads retired
        if (kc0 + 4 < K8) stage(kc0 + 4, buf ^ 1);

        f16x8 af[4], bf[4];
#pragma unroll
        for (int i = 0; i < 4; ++i) {
            af[i] = *(const f16x8*)&sA[buf][q][wm + i * 16 + m15][0];
            bf[i] = *(const f16x8*)&sB[buf][q][wn + i * 16 + m15][0];
        }
#pragma unroll
        for (int i = 0; i < 4; ++i)
#pragma unroll
            for (int j = 0; j < 4; ++j)
                acc[i][j] = __builtin_amdgcn_mfma_f32_16x16x32_f16(af[i], bf[j], acc[i][j], 0, 0, 0);
    }

    const int r4 = (lane >> 4) * 4;   // C/D: col=lane&15, row=(lane>>4)*4+reg (m89)
#pragma unroll
    for (int j = 0; j < 4; ++j) {
        int col = bn * 128 + wn + j * 16 + m15;
        float bv = bias[col];
#pragma unroll
        for (int i = 0; i < 4; ++i) {
            int row0 = bm * 128 + wm + i * 16 + r4;
#pragma unroll
            for (int r = 0; r < 4; ++r)
                C[(size_t)(row0 + r) * LDC + col] = acc[i][j][r] + bv;
        }
    }
}

// ---- scan: U[t] = p*U[t-1] + p0*h[t], U[-1]=last;  z[t]=Re(U[t]); y=silu(z) ----
__device__ inline void compute_p(const float* __restrict__ phazor, int c, float& pre, float& pim) {
    float zr = phazor[2 * c], zi = phazor[2 * c + 1];
    float pa = sqrtf(zr * zr + zi * zi);
    float sc = expf(-pa) / pa;       // unit phase * exp(-|p|) magnitude
    pre = zr * sc;
    pim = zi * sc;
}

// phase 1: per-chunk local scan (init 0), write chunk-end state
__global__ void scan_local(const float* __restrict__ h, const float* __restrict__ phazor,
                           const float* __restrict__ phazor_init, float* __restrict__ Uend) {
    int idx = blockIdx.x * blockDim.x + threadIdx.x;      // [0, B*NCH*DH)
    if (idx >= WS_B * NCH * WS_DH) return;
    int c  = idx & (WS_DH - 1);
    int bj = idx >> 11;
    int j  = bj & (NCH - 1);
    int b  = bj >> 5;
    float pre, pim;
    compute_p(phazor, c, pre, pim);
    float p0r = phazor_init[2 * c], p0i = phazor_init[2 * c + 1];
    const float* hp = h + ((size_t)(b * WS_L + j * CHUNK)) * WS_DH + c;
    float ur = 0.f, ui = 0.f;
    for (int t = 0; t < CHUNK; t += 8) {
        float hv[8];
#pragma unroll
        for (int u = 0; u < 8; ++u) hv[u] = hp[(size_t)(t + u) * WS_DH];
#pragma unroll
        for (int u = 0; u < 8; ++u) {
            float nr = fmaf(pre, ur, fmaf(-pim, ui, p0r * hv[u]));
            float ni = fmaf(pre, ui, fmaf( pim, ur, p0i * hv[u]));
            ur = nr; ui = ni;
        }
    }
    Uend[2 * idx] = ur;
    Uend[2 * idx + 1] = ui;
}

// phase 2: serial combine over chunks; carry[j] = full state entering chunk j
__global__ void scan_carry(const float* __restrict__ Uend, float* __restrict__ carry,
                           const float* __restrict__ phazor,
                           const float* __restrict__ last_re, const float* __restrict__ last_im) {
    int idx = blockIdx.x * blockDim.x + threadIdx.x;      // [0, B*DH)
    if (idx >= WS_B * WS_DH) return;
    int c = idx & (WS_DH - 1);
    int b = idx >> 11;
    float pre, pim;
    compute_p(phazor, c, pre, pim);
    float qr = pre, qi = pim;                              // p^CHUNK via 6 squarings (CHUNK=64)
#pragma unroll
    for (int s = 0; s < 6; ++s) {
        float nr = qr * qr - qi * qi;
        qi = 2.f * qr * qi;
        qr = nr;
    }
    float ur = last_re[idx], ui = last_im[idx];            // U[-1] = last
    for (int j = 0; j < NCH; ++j) {
        int o = (b * NCH + j) * WS_DH + c;
        carry[2 * o] = ur;
        carry[2 * o + 1] = ui;
        float Lr = Uend[2 * o], Li = Uend[2 * o + 1];
        float nr = fmaf(qr, ur, fmaf(-qi, ui, Lr));
        float ni = fmaf(qr, ui, fmaf( qi, ur, Li));
        ur = nr; ui = ni;
    }
}

// phase 3: re-scan from carry, silu, write y (fp16, single-rounded) DIRECTLY in
// packed tile-major layout P[rb][kc][r][8] (K8=256).
__global__ void scan_apply(const float* __restrict__ h, const float* __restrict__ phazor,
                           const float* __restrict__ phazor_init, const float* __restrict__ carry,
                           _Float16* __restrict__ yh) {
    int idx = blockIdx.x * blockDim.x + threadIdx.x;
    if (idx >= WS_B * NCH * WS_DH) return;
    int c  = idx & (WS_DH - 1);
    int bj = idx >> 11;
    int j  = bj & (NCH - 1);
    int b  = bj >> 5;
    float pre, pim;
    compute_p(phazor, c, pre, pim);
    float p0r = phazor_init[2 * c], p0i = phazor_init[2 * c + 1];
    float ur = carry[2 * idx], ui = carry[2 * idx + 1];
    const int row0 = b * WS_L + j * CHUNK;
    const float* hp = h + (size_t)row0 * WS_DH + c;
    const int chi = c >> 3, clo = c & 7;                   // packed column split
    for (int t = 0; t < CHUNK; t += 8) {
        float hv[8];
#pragma unroll
        for (int u = 0; u < 8; ++u) hv[u] = hp[(size_t)(t + u) * WS_DH];
#pragma unroll
        for (int u = 0; u < 8; ++u) {
            float nr = fmaf(pre, ur, fmaf(-pim, ui, p0r * hv[u]));
            float ni = fmaf(pre, ui, fmaf( pim, ur, p0i * hv[u]));
            ur = nr; ui = ni;
            float z  = ur;                                  // Re(U[t])
            float yv = z / (1.f + expf(-z));                // silu
            int row = row0 + t + u;
            size_t o = (((size_t)(row >> 7) * 256 + chi) * 128 + (row & 127)) * 8 + clo;
            yh[o] = (_Float16)yv;
        }
    }
}

extern "C" void kernel_launch(void* const* d_in, const int* in_sizes, int n_in,
                              void* d_out, int out_size, void* d_ws, size_t ws_size,
                              hipStream_t stream)
{
    const float* x       = (const float*)d_in[0];
    const float* W_in    = (const float*)d_in[1];
    const float* b_in    = (const float*)d_in[2];
    const float* W_out   = (const float*)d_in[3];
    const float* b_out   = (const float*)d_in[4];
    const float* phazor  = (const float*)d_in[5];
    const float* ph_init = (const float*)d_in[6];
    const float* last_re = (const float*)d_in[7];
    const float* last_im = (const float*)d_in[8];
    float* out = (float*)d_out;

    // workspace carve-up (~124 MB)
    char* ws = (char*)d_ws;
    size_t off = 0;
    auto alloc = [&](size_t bytes) {
        char* p = ws + off;
        off += (bytes + 255) & ~(size_t)255;
        return p;
    };
    _Float16* xp    = (_Float16*)alloc((size_t)WS_M * WS_D * 2);     // 16 MB packed
    _Float16* w1p   = (_Float16*)alloc((size_t)WS_DH * WS_D * 2);    //  4 MB packed
    _Float16* w2p   = (_Float16*)alloc((size_t)WS_D * WS_DH * 2);    //  4 MB packed
    float*    h     = (float*)alloc((size_t)WS_M * WS_DH * 4);       // 64 MB
    _Float16* yhp   = (_Float16*)alloc((size_t)WS_M * WS_DH * 2);    // 32 MB packed
    float*    Uend  = (float*)alloc((size_t)WS_B * NCH * WS_DH * 2 * 4);
    float*    carry = (float*)alloc((size_t)WS_B * NCH * WS_DH * 2 * 4);

    // 1) pack inputs to fp16 tile-major
    {
        int n = WS_M * WS_D / 8;      // x: R=8192, K=1024, K8=128 (log 7)
        pack_f16<<<dim3((n + 255) / 256), dim3(256), 0, stream>>>(x, xp, WS_D, 7, n);
        n = WS_DH * WS_D / 8;         // W_in: R=2048, K=1024
        pack_f16<<<dim3((n + 255) / 256), dim3(256), 0, stream>>>(W_in, w1p, WS_D, 7, n);
        n = WS_D * WS_DH / 8;         // W_out: R=1024, K=2048, K8=256 (log 8)
        pack_f16<<<dim3((n + 255) / 256), dim3(256), 0, stream>>>(W_out, w2p, WS_DH, 8, n);
    }

    // 2) h = x @ W_in^T + b_in   [8192, 2048], grid 64x16 = 1024 blocks
    {
        dim3 g(WS_M / 128, WS_DH / 128);
        gemm_f16_packed<WS_D / 8, WS_DH><<<g, dim3(256), 0, stream>>>(xp, w1p, b_in, h);
    }

    // 3) chunked complex scan + silu -> yh (fp16, packed)
    {
        int total = WS_B * NCH * WS_DH;
        scan_local<<<dim3(total / 256), dim3(256), 0, stream>>>(h, phazor, ph_init, Uend);
        scan_carry<<<dim3(WS_B * WS_DH / 256), dim3(256), 0, stream>>>(Uend, carry, phazor,
                                                                       last_re, last_im);
        scan_apply<<<dim3(total / 256), dim3(256), 0, stream>>>(h, phazor, ph_init, carry, yhp);
    }

    // 4) out = yh @ W_out^T + b_out, K=2048, grid 64x8 = 512 blocks
    {
        dim3 g(WS_M / 128, WS_D / 128);
        gemm_f16_packed<WS_DH / 8, WS_D><<<g, dim3(256), 0, stream>>>(yhp, w2p, b_out, out);
    }
}